// Round 2
// baseline (653.122 us; speedup 1.0000x reference)
//
#include <hip/hip_runtime.h>
#include <hip/hip_bf16.h>

// ---- problem dims (compile-time) ----
#define DIM     1024
#define DINNER  2048
#define NSTATE  16
#define DTRANK  64
#define DCONV   4
#define BATCH   2
#define SEQ     1024
#define BL      (BATCH*SEQ)     // 2048 rows
#define XDBLW   96              // DTRANK + 2*NSTATE

typedef __attribute__((ext_vector_type(4))) float  f32x4;
typedef __attribute__((ext_vector_type(8))) short  bf16x8;
typedef unsigned short ushort_t;

__device__ __forceinline__ ushort_t f2bf(float f) {
    union { float f; unsigned int u; } v; v.f = f;
    unsigned int lsb = (v.u >> 16) & 1u;
    v.u += 0x7fffu + lsb;
    return (ushort_t)(v.u >> 16);
}

// ---------------- convert f32 -> bf16 (flat) ----------------
__global__ __launch_bounds__(256) void cvt_f32_bf16(
    const float* __restrict__ src, ushort_t* __restrict__ dst, int n)
{
    int i = (blockIdx.x * 256 + threadIdx.x) * 4;
    if (i >= n) return;
    f32x4 v = *(const f32x4*)(src + i);
    ushort_t r0 = f2bf(v[0]), r1 = f2bf(v[1]), r2 = f2bf(v[2]), r3 = f2bf(v[3]);
    *(uint2*)(dst + i) = make_uint2((unsigned)r0 | ((unsigned)r1 << 16),
                                    (unsigned)r2 | ((unsigned)r3 << 16));
}

// ---------------- transpose f32 (R x C) -> bf16 (C x R), 32x32 tiles ----------------
__global__ __launch_bounds__(256) void transpose_f32_bf16(
    const float* __restrict__ src, ushort_t* __restrict__ dst, int R, int C)
{
    __shared__ float tile[32][33];
    const int tx = threadIdx.x;      // 0..31
    const int ty = threadIdx.y;      // 0..7
    const int r0 = blockIdx.y * 32;
    const int c0 = blockIdx.x * 32;
    #pragma unroll
    for (int i = 0; i < 4; ++i) {
        int r = r0 + ty + i * 8;
        tile[ty + i * 8][tx] = src[(size_t)r * C + c0 + tx];
    }
    __syncthreads();
    #pragma unroll
    for (int i = 0; i < 4; ++i) {
        int c = c0 + ty + i * 8;
        dst[(size_t)c * R + r0 + tx] = f2bf(tile[tx][ty + i * 8]);
    }
}

// ---------------- generic bf16 MFMA GEMM: C = A(MxK) * B^T(NxK)^T ----------------
// 128x128 tile, 256 threads = 4 waves, each wave 64x64 (4x4 frags of 16x16x32).
// M multiple of 128, K multiple of 32. N arbitrary (guarded).
__global__ __launch_bounds__(256) void gemm_bt(
    const ushort_t* __restrict__ A,  int lda,
    const ushort_t* __restrict__ Bt, int ldb,
    int M, int N, int K,
    float* __restrict__ Cf, ushort_t* __restrict__ Cb, int ldc,
    const float* __restrict__ bias, int do_softplus)
{
    __shared__ ushort_t As[128 * 40];   // +8 pad -> 80B row stride (2-way bank alias, free)
    __shared__ ushort_t Bs[128 * 40];

    const int tid  = threadIdx.x;
    const int m0   = blockIdx.y * 128;
    const int n0   = blockIdx.x * 128;
    const int wid  = tid >> 6;
    const int lane = tid & 63;
    const int wm   = (wid >> 1) * 64;
    const int wn   = (wid & 1) * 64;
    const int lr   = lane & 15;
    const int lk   = (lane >> 4) * 8;

    f32x4 acc[4][4];
    #pragma unroll
    for (int m = 0; m < 4; ++m)
        #pragma unroll
        for (int n = 0; n < 4; ++n)
            acc[m][n] = (f32x4){0.f, 0.f, 0.f, 0.f};

    for (int k0 = 0; k0 < K; k0 += 32) {
        // stage A-tile and B-tile: 512 16B-chunks each / 256 threads
        #pragma unroll
        for (int c = 0; c < 2; ++c) {
            int cid = tid + c * 256;
            int row = cid >> 2;
            int ck  = (cid & 3) * 8;
            uint4 va = *(const uint4*)(A + (size_t)(m0 + row) * lda + k0 + ck);
            *(uint4*)(&As[row * 40 + ck]) = va;
            int bn = n0 + row;
            uint4 vb = make_uint4(0u, 0u, 0u, 0u);
            if (bn < N) vb = *(const uint4*)(Bt + (size_t)bn * ldb + k0 + ck);
            *(uint4*)(&Bs[row * 40 + ck]) = vb;
        }
        __syncthreads();

        bf16x8 af[4], bfr[4];
        #pragma unroll
        for (int m = 0; m < 4; ++m)
            af[m] = *(const bf16x8*)(&As[(wm + m * 16 + lr) * 40 + lk]);
        #pragma unroll
        for (int n = 0; n < 4; ++n)
            bfr[n] = *(const bf16x8*)(&Bs[(wn + n * 16 + lr) * 40 + lk]);

        #pragma unroll
        for (int m = 0; m < 4; ++m)
            #pragma unroll
            for (int n = 0; n < 4; ++n)
                acc[m][n] = __builtin_amdgcn_mfma_f32_16x16x32_bf16(af[m], bfr[n], acc[m][n], 0, 0, 0);
        __syncthreads();
    }

    // epilogue: C/D layout col = lane&15, row = (lane>>4)*4 + r   [m89]
    const int rbase = (lane >> 4) * 4;
    #pragma unroll
    for (int m = 0; m < 4; ++m) {
        #pragma unroll
        for (int n = 0; n < 4; ++n) {
            int col = n0 + wn + n * 16 + lr;
            if (col >= N) continue;
            #pragma unroll
            for (int r = 0; r < 4; ++r) {
                int row = m0 + wm + m * 16 + rbase + r;
                float v = acc[m][n][r];
                if (do_softplus) {
                    v += bias[col];
                    v = (v > 20.f) ? v : log1pf(expf(v));
                }
                if (Cf) Cf[(size_t)row * ldc + col] = v;
                if (Cb) Cb[(size_t)row * ldc + col] = f2bf(v);
            }
        }
    }
}

// ---------------- depthwise causal conv(4) + bias + SiLU ----------------
// xr: BL x 4096 f32 (xp = cols [0,2048));  h out in f32 and bf16 (BL x 2048)
__global__ __launch_bounds__(256) void conv_silu(
    const float* __restrict__ xr,
    const float* __restrict__ convw,   // 2048 x 4
    const float* __restrict__ convb,   // 2048
    float* __restrict__ hf, ushort_t* __restrict__ hb)
{
    const int d  = blockIdx.x * 256 + threadIdx.x;  // 0..2047
    const int bt = blockIdx.y;                      // 0..2047
    const int t  = bt & (SEQ - 1);

    float acc = convb[d];
    #pragma unroll
    for (int j = 0; j < DCONV; ++j) {
        int tt = t + j - (DCONV - 1);
        if (tt >= 0)
            acc += convw[d * DCONV + j] * xr[(size_t)(bt + j - (DCONV - 1)) * 4096 + d];
    }
    float h = acc / (1.f + expf(-acc));   // silu
    hf[(size_t)bt * DINNER + d] = h;
    hb[(size_t)bt * DINNER + d] = f2bf(h);
}

// ---------------- selective scan ----------------
// 16 lanes per (b,d) chain, one lane per state n. 4096 chains, 256 blocks x 256 thr.
__global__ __launch_bounds__(256) void scan_kernel(
    const float* __restrict__ delta,   // BL x 2048
    const float* __restrict__ hf,      // BL x 2048
    const float* __restrict__ xdbl,    // BL x 96  (B at +64, C at +80)
    const float* __restrict__ xr,      // BL x 4096 (res at +2048)
    const float* __restrict__ Alog,    // 2048 x 16
    const float* __restrict__ Dp,      // 2048
    ushort_t* __restrict__ yb)         // BL x 2048
{
    const int tid   = threadIdx.x;
    const int n     = tid & 15;
    const int cib   = tid >> 4;
    const int chain = blockIdx.x * 16 + cib;   // 0..4095
    const int b     = chain >> 11;
    const int d     = chain & (DINNER - 1);

    const float An = -expf(Alog[d * NSTATE + n]);
    const float Dd = Dp[d];
    float state = 0.f;
    const size_t base = (size_t)b * SEQ;

    // prefetch t = 0
    float dl = delta[base * DINNER + d];
    float hv = hf[base * DINNER + d];
    float Bn = xdbl[base * XDBLW + DTRANK + n];
    float Cn = xdbl[base * XDBLW + DTRANK + NSTATE + n];
    float rv = xr[base * 4096 + DINNER + d];

    for (int t = 0; t < SEQ; ++t) {
        float dl_c = dl, hv_c = hv, Bn_c = Bn, Cn_c = Cn, rv_c = rv;
        if (t + 1 < SEQ) {
            size_t r = base + t + 1;
            dl = delta[r * DINNER + d];
            hv = hf[r * DINNER + d];
            Bn = xdbl[r * XDBLW + DTRANK + n];
            Cn = xdbl[r * XDBLW + DTRANK + NSTATE + n];
            rv = xr[r * 4096 + DINNER + d];
        }
        state = expf(dl_c * An) * state + (dl_c * hv_c) * Bn_c;
        float p = state * Cn_c;
        p += __shfl_xor(p, 1, 64);
        p += __shfl_xor(p, 2, 64);
        p += __shfl_xor(p, 4, 64);
        p += __shfl_xor(p, 8, 64);
        float y = p + hv_c * Dd;
        float sig = 1.f / (1.f + expf(-rv_c));
        y *= rv_c * sig;
        if (n == 0) yb[(base + t) * DINNER + d] = f2bf(y);
    }
}

extern "C" void kernel_launch(void* const* d_in, const int* in_sizes, int n_in,
                              void* d_out, int out_size, void* d_ws, size_t ws_size,
                              hipStream_t stream)
{
    const float* x     = (const float*)d_in[0];  // 2 x 1024 x 1024
    const float* Win   = (const float*)d_in[1];  // 1024 x 4096
    const float* convw = (const float*)d_in[2];  // 2048 x 1 x 4
    const float* convb = (const float*)d_in[3];  // 2048
    const float* Wxp   = (const float*)d_in[4];  // 2048 x 96
    const float* Wdt   = (const float*)d_in[5];  // 64 x 2048
    const float* dtb   = (const float*)d_in[6];  // 2048
    const float* Alog  = (const float*)d_in[7];  // 2048 x 16
    const float* Dp    = (const float*)d_in[8];  // 2048
    const float* Wout  = (const float*)d_in[9];  // 2048 x 1024
    float* out = (float*)d_out;                  // 2 x 1024 x 1024 (f32)

    char* base = (char*)d_ws; size_t off = 0;
    auto alloc = [&](size_t bytes) -> char* {
        char* q = base + off;
        off = (off + bytes + 255) & ~(size_t)255;
        return q;
    };
    ushort_t* WtIn  = (ushort_t*)alloc((size_t)4096 * 1024 * 2);  // in_proj_w^T  bf16
    ushort_t* WtOut = (ushort_t*)alloc((size_t)1024 * 2048 * 2);  // out_proj_w^T bf16
    ushort_t* WtXp  = (ushort_t*)alloc((size_t)96   * 2048 * 2);  // x_proj_w^T   bf16
    ushort_t* WtDt  = (ushort_t*)alloc((size_t)2048 * 64   * 2);  // dt_proj_w^T  bf16
    ushort_t* xb    = (ushort_t*)alloc((size_t)BL * DIM * 2);     // x bf16
    float*    xr    = (float*)   alloc((size_t)BL * 4096 * 4);    // x @ in_proj_w (f32)
    float*    hf    = (float*)   alloc((size_t)BL * DINNER * 4);
    ushort_t* hb    = (ushort_t*)alloc((size_t)BL * DINNER * 2);
    float*    xdbl  = (float*)   alloc((size_t)BL * XDBLW * 4);
    ushort_t* xdblb = (ushort_t*)alloc((size_t)BL * XDBLW * 2);
    float*    delta = (float*)   alloc((size_t)BL * DINNER * 4);
    ushort_t* yb    = (ushort_t*)alloc((size_t)BL * DINNER * 2);
    (void)ws_size;

    dim3 tb(32, 8);
    // weight transposes + bf16 convert (K x N -> N x K)
    transpose_f32_bf16<<<dim3(4096/32, 1024/32), tb, 0, stream>>>(Win,  WtIn,  1024, 4096);
    transpose_f32_bf16<<<dim3(1024/32, 2048/32), tb, 0, stream>>>(Wout, WtOut, 2048, 1024);
    transpose_f32_bf16<<<dim3(96/32,   2048/32), tb, 0, stream>>>(Wxp,  WtXp,  2048, 96);
    transpose_f32_bf16<<<dim3(2048/32, 64/32),   tb, 0, stream>>>(Wdt,  WtDt,  64,   2048);
    // x -> bf16
    cvt_f32_bf16<<<dim3((BL*DIM/4 + 255)/256), 256, 0, stream>>>(x, xb, BL*DIM);

    // G1: xr = x @ in_proj_w   (2048 x 4096, K=1024)
    gemm_bt<<<dim3(4096/128, BL/128), 256, 0, stream>>>(
        xb, DIM, WtIn, DIM, BL, 2*DINNER, DIM, xr, nullptr, 2*DINNER, nullptr, 0);

    // conv + silu -> h (f32 + bf16)
    conv_silu<<<dim3(DINNER/256, BL), 256, 0, stream>>>(xr, convw, convb, hf, hb);

    // G2: xdbl = h @ x_proj_w  (2048 x 96, K=2048), f32 + bf16 copies
    gemm_bt<<<dim3(1, BL/128), 256, 0, stream>>>(
        hb, DINNER, WtXp, DINNER, BL, XDBLW, DINNER, xdbl, xdblb, XDBLW, nullptr, 0);

    // G3: delta = softplus(dlt @ dt_proj_w + dt_b)  (2048 x 2048, K=64)
    gemm_bt<<<dim3(DINNER/128, BL/128), 256, 0, stream>>>(
        xdblb, XDBLW, WtDt, DTRANK, BL, DINNER, DTRANK, delta, nullptr, DINNER, dtb, 1);

    // selective scan -> y (bf16), fused +h*D and *silu(res)
    scan_kernel<<<dim3(256), 256, 0, stream>>>(delta, hf, xdbl, xr, Alog, Dp, yb);

    // G4: out = y @ out_proj_w (2048 x 1024, K=2048) -> f32 d_out
    gemm_bt<<<dim3(DIM/128, BL/128), 256, 0, stream>>>(
        yb, DINNER, WtOut, DINNER, BL, DIM, DINNER, out, nullptr, DIM, nullptr, 0);
}

// Round 3
// 352.680 us; speedup vs baseline: 1.8519x; 1.8519x over previous
//
#include <hip/hip_runtime.h>
#include <hip/hip_bf16.h>

// ---- problem dims (compile-time) ----
#define DIM     1024
#define DINNER  2048
#define NSTATE  16
#define DTRANK  64
#define DCONV   4
#define BATCH   2
#define SEQ     1024
#define BL      (BATCH*SEQ)     // 2048 rows
#define XDBLW   96              // DTRANK + 2*NSTATE
#define NCHUNK  64
#define TCHUNK  16              // SEQ / NCHUNK

typedef __attribute__((ext_vector_type(4))) float  f32x4;
typedef __attribute__((ext_vector_type(8))) short  bf16x8;
typedef unsigned short ushort_t;

__device__ __forceinline__ ushort_t f2bf(float f) {
    union { float f; unsigned int u; } v; v.f = f;
    unsigned int lsb = (v.u >> 16) & 1u;
    v.u += 0x7fffu + lsb;
    return (ushort_t)(v.u >> 16);
}

// ---------------- convert f32 -> bf16 (flat) ----------------
__global__ __launch_bounds__(256) void cvt_f32_bf16(
    const float* __restrict__ src, ushort_t* __restrict__ dst, int n)
{
    int i = (blockIdx.x * 256 + threadIdx.x) * 4;
    if (i >= n) return;
    f32x4 v = *(const f32x4*)(src + i);
    ushort_t r0 = f2bf(v[0]), r1 = f2bf(v[1]), r2 = f2bf(v[2]), r3 = f2bf(v[3]);
    *(uint2*)(dst + i) = make_uint2((unsigned)r0 | ((unsigned)r1 << 16),
                                    (unsigned)r2 | ((unsigned)r3 << 16));
}

// ---------------- transpose f32 (R x C) -> bf16 (C x R), 32x32 tiles ----------------
__global__ __launch_bounds__(256) void transpose_f32_bf16(
    const float* __restrict__ src, ushort_t* __restrict__ dst, int R, int C)
{
    __shared__ float tile[32][33];
    const int tx = threadIdx.x;      // 0..31
    const int ty = threadIdx.y;      // 0..7
    const int r0 = blockIdx.y * 32;
    const int c0 = blockIdx.x * 32;
    #pragma unroll
    for (int i = 0; i < 4; ++i) {
        int r = r0 + ty + i * 8;
        tile[ty + i * 8][tx] = src[(size_t)r * C + c0 + tx];
    }
    __syncthreads();
    #pragma unroll
    for (int i = 0; i < 4; ++i) {
        int c = c0 + ty + i * 8;
        dst[(size_t)c * R + r0 + tx] = f2bf(tile[tx][ty + i * 8]);
    }
}

// ---------------- generic bf16 MFMA GEMM: C = A(MxK) * B^T(NxK)^T ----------------
__global__ __launch_bounds__(256) void gemm_bt(
    const ushort_t* __restrict__ A,  int lda,
    const ushort_t* __restrict__ Bt, int ldb,
    int M, int N, int K,
    float* __restrict__ Cf, ushort_t* __restrict__ Cb, int ldc,
    const float* __restrict__ bias, int do_softplus)
{
    __shared__ ushort_t As[128 * 40];
    __shared__ ushort_t Bs[128 * 40];

    const int tid  = threadIdx.x;
    const int m0   = blockIdx.y * 128;
    const int n0   = blockIdx.x * 128;
    const int wid  = tid >> 6;
    const int lane = tid & 63;
    const int wm   = (wid >> 1) * 64;
    const int wn   = (wid & 1) * 64;
    const int lr   = lane & 15;
    const int lk   = (lane >> 4) * 8;

    f32x4 acc[4][4];
    #pragma unroll
    for (int m = 0; m < 4; ++m)
        #pragma unroll
        for (int n = 0; n < 4; ++n)
            acc[m][n] = (f32x4){0.f, 0.f, 0.f, 0.f};

    for (int k0 = 0; k0 < K; k0 += 32) {
        #pragma unroll
        for (int c = 0; c < 2; ++c) {
            int cid = tid + c * 256;
            int row = cid >> 2;
            int ck  = (cid & 3) * 8;
            uint4 va = *(const uint4*)(A + (size_t)(m0 + row) * lda + k0 + ck);
            *(uint4*)(&As[row * 40 + ck]) = va;
            int bn = n0 + row;
            uint4 vb = make_uint4(0u, 0u, 0u, 0u);
            if (bn < N) vb = *(const uint4*)(Bt + (size_t)bn * ldb + k0 + ck);
            *(uint4*)(&Bs[row * 40 + ck]) = vb;
        }
        __syncthreads();

        bf16x8 af[4], bfr[4];
        #pragma unroll
        for (int m = 0; m < 4; ++m)
            af[m] = *(const bf16x8*)(&As[(wm + m * 16 + lr) * 40 + lk]);
        #pragma unroll
        for (int n = 0; n < 4; ++n)
            bfr[n] = *(const bf16x8*)(&Bs[(wn + n * 16 + lr) * 40 + lk]);

        #pragma unroll
        for (int m = 0; m < 4; ++m)
            #pragma unroll
            for (int n = 0; n < 4; ++n)
                acc[m][n] = __builtin_amdgcn_mfma_f32_16x16x32_bf16(af[m], bfr[n], acc[m][n], 0, 0, 0);
        __syncthreads();
    }

    const int rbase = (lane >> 4) * 4;
    #pragma unroll
    for (int m = 0; m < 4; ++m) {
        #pragma unroll
        for (int n = 0; n < 4; ++n) {
            int col = n0 + wn + n * 16 + lr;
            if (col >= N) continue;
            #pragma unroll
            for (int r = 0; r < 4; ++r) {
                int row = m0 + wm + m * 16 + rbase + r;
                float v = acc[m][n][r];
                if (do_softplus) {
                    v += bias[col];
                    v = (v > 20.f) ? v : log1pf(expf(v));
                }
                if (Cf) Cf[(size_t)row * ldc + col] = v;
                if (Cb) Cb[(size_t)row * ldc + col] = f2bf(v);
            }
        }
    }
}

// ---------------- depthwise causal conv(4) + bias + SiLU ----------------
__global__ __launch_bounds__(256) void conv_silu(
    const float* __restrict__ xr,
    const float* __restrict__ convw,   // 2048 x 4
    const float* __restrict__ convb,   // 2048
    float* __restrict__ hf, ushort_t* __restrict__ hb)
{
    const int d  = blockIdx.x * 256 + threadIdx.x;  // 0..2047
    const int bt = blockIdx.y;                      // 0..2047
    const int t  = bt & (SEQ - 1);

    float acc = convb[d];
    #pragma unroll
    for (int j = 0; j < DCONV; ++j) {
        int tt = t + j - (DCONV - 1);
        if (tt >= 0)
            acc += convw[d * DCONV + j] * xr[(size_t)(bt + j - (DCONV - 1)) * 4096 + d];
    }
    float h = acc / (1.f + expf(-acc));   // silu
    hf[(size_t)bt * DINNER + d] = h;
    hb[(size_t)bt * DINNER + d] = f2bf(h);
}

// ================= chunked parallel selective scan =================
// thread = (b, chunk, d); all 16 states in registers.
// P1: per-chunk decay product P[n] and zero-init final state S[n].
__global__ __launch_bounds__(256) void scan_p1(
    const float* __restrict__ delta,   // BL x 2048
    const float* __restrict__ hf,      // BL x 2048
    const float* __restrict__ xdbl,    // BL x 96 (B at +64)
    const float* __restrict__ Alog,    // 2048 x 16
    float* __restrict__ Pbuf,          // [B][NCHUNK][D][N]
    float* __restrict__ Sbuf)          // [B][NCHUNK][D][N]
{
    const int d  = (blockIdx.x & 7) * 256 + threadIdx.x;
    const int bc = blockIdx.x >> 3;
    const int b  = bc >> 6;
    const int c  = bc & (NCHUNK - 1);
    const int t0 = c * TCHUNK;

    float A[NSTATE];
    #pragma unroll
    for (int q = 0; q < 4; ++q) {
        f32x4 al = *(const f32x4*)(Alog + (size_t)d * NSTATE + q * 4);
        #pragma unroll
        for (int j = 0; j < 4; ++j) A[q * 4 + j] = -expf(al[j]);
    }

    float s[NSTATE], pp[NSTATE];
    #pragma unroll
    for (int n = 0; n < NSTATE; ++n) { s[n] = 0.f; pp[n] = 1.f; }

    for (int tt = 0; tt < TCHUNK; ++tt) {
        const size_t row = (size_t)(b * SEQ + t0 + tt);
        float dl = delta[row * DINNER + d];
        float hv = hf[row * DINNER + d];
        float dlh = dl * hv;
        float Bv[NSTATE];
        #pragma unroll
        for (int q = 0; q < 4; ++q) {
            f32x4 bv = *(const f32x4*)(xdbl + row * XDBLW + DTRANK + q * 4);
            #pragma unroll
            for (int j = 0; j < 4; ++j) Bv[q * 4 + j] = bv[j];
        }
        #pragma unroll
        for (int n = 0; n < NSTATE; ++n) {
            float a = expf(dl * A[n]);
            s[n]  = fmaf(a, s[n], dlh * Bv[n]);
            pp[n] *= a;
        }
    }

    const size_t o = (((size_t)b * NCHUNK + c) * DINNER + d) * NSTATE;
    #pragma unroll
    for (int q = 0; q < 4; ++q) {
        *(f32x4*)(Sbuf + o + q * 4) = (f32x4){s[q*4+0], s[q*4+1], s[q*4+2], s[q*4+3]};
        *(f32x4*)(Pbuf + o + q * 4) = (f32x4){pp[q*4+0], pp[q*4+1], pp[q*4+2], pp[q*4+3]};
    }
}

// P2: sequential carry over chunk summaries; overwrites Sbuf[c] with the
// carry-IN state for chunk c. thread = (b,d,n).
__global__ __launch_bounds__(256) void scan_p2(
    const float* __restrict__ Pbuf, float* __restrict__ Sbuf)
{
    const int tid = blockIdx.x * 256 + threadIdx.x;   // 0..65535
    const int n = tid & 15;
    const int d = (tid >> 4) & (DINNER - 1);
    const int b = tid >> 15;
    const size_t stride = (size_t)DINNER * NSTATE;
    size_t idx = ((size_t)b * NCHUNK * DINNER + d) * NSTATE + n;
    float cin = 0.f;
    for (int c = 0; c < NCHUNK; ++c, idx += stride) {
        float S = Sbuf[idx];
        float P = Pbuf[idx];
        Sbuf[idx] = cin;
        cin = fmaf(P, cin, S);
    }
}

// P3: re-run each chunk with correct carry-in, emit y (fused D, silu(res), bf16).
__global__ __launch_bounds__(256) void scan_p3(
    const float* __restrict__ delta,
    const float* __restrict__ hf,
    const float* __restrict__ xdbl,    // B at +64, C at +80
    const float* __restrict__ xr,      // res at +2048
    const float* __restrict__ Alog,
    const float* __restrict__ Dp,
    const float* __restrict__ Sbuf,    // carry-in per chunk
    ushort_t* __restrict__ yb)
{
    const int d  = (blockIdx.x & 7) * 256 + threadIdx.x;
    const int bc = blockIdx.x >> 3;
    const int b  = bc >> 6;
    const int c  = bc & (NCHUNK - 1);
    const int t0 = c * TCHUNK;

    float A[NSTATE];
    #pragma unroll
    for (int q = 0; q < 4; ++q) {
        f32x4 al = *(const f32x4*)(Alog + (size_t)d * NSTATE + q * 4);
        #pragma unroll
        for (int j = 0; j < 4; ++j) A[q * 4 + j] = -expf(al[j]);
    }
    const float Dd = Dp[d];

    float s[NSTATE];
    const size_t o = (((size_t)b * NCHUNK + c) * DINNER + d) * NSTATE;
    #pragma unroll
    for (int q = 0; q < 4; ++q) {
        f32x4 sv = *(const f32x4*)(Sbuf + o + q * 4);
        #pragma unroll
        for (int j = 0; j < 4; ++j) s[q * 4 + j] = sv[j];
    }

    for (int tt = 0; tt < TCHUNK; ++tt) {
        const size_t row = (size_t)(b * SEQ + t0 + tt);
        float dl = delta[row * DINNER + d];
        float hv = hf[row * DINNER + d];
        float rv = xr[row * 4096 + DINNER + d];
        float dlh = dl * hv;
        float Bv[NSTATE], Cv[NSTATE];
        #pragma unroll
        for (int q = 0; q < 4; ++q) {
            f32x4 bv = *(const f32x4*)(xdbl + row * XDBLW + DTRANK + q * 4);
            f32x4 cv = *(const f32x4*)(xdbl + row * XDBLW + DTRANK + NSTATE + q * 4);
            #pragma unroll
            for (int j = 0; j < 4; ++j) { Bv[q*4+j] = bv[j]; Cv[q*4+j] = cv[j]; }
        }
        float y = 0.f;
        #pragma unroll
        for (int n = 0; n < NSTATE; ++n) {
            float a = expf(dl * A[n]);
            s[n] = fmaf(a, s[n], dlh * Bv[n]);
            y = fmaf(s[n], Cv[n], y);
        }
        y = fmaf(hv, Dd, y);
        float sig = 1.f / (1.f + expf(-rv));
        y *= rv * sig;
        yb[row * DINNER + d] = f2bf(y);
    }
}

extern "C" void kernel_launch(void* const* d_in, const int* in_sizes, int n_in,
                              void* d_out, int out_size, void* d_ws, size_t ws_size,
                              hipStream_t stream)
{
    const float* x     = (const float*)d_in[0];
    const float* Win   = (const float*)d_in[1];
    const float* convw = (const float*)d_in[2];
    const float* convb = (const float*)d_in[3];
    const float* Wxp   = (const float*)d_in[4];
    const float* Wdt   = (const float*)d_in[5];
    const float* dtb   = (const float*)d_in[6];
    const float* Alog  = (const float*)d_in[7];
    const float* Dp    = (const float*)d_in[8];
    const float* Wout  = (const float*)d_in[9];
    float* out = (float*)d_out;

    char* base = (char*)d_ws; size_t off = 0;
    auto alloc = [&](size_t bytes) -> char* {
        char* q = base + off;
        off = (off + bytes + 255) & ~(size_t)255;
        return q;
    };
    ushort_t* WtIn  = (ushort_t*)alloc((size_t)4096 * 1024 * 2);
    ushort_t* WtOut = (ushort_t*)alloc((size_t)1024 * 2048 * 2);
    ushort_t* WtXp  = (ushort_t*)alloc((size_t)96   * 2048 * 2);
    ushort_t* WtDt  = (ushort_t*)alloc((size_t)2048 * 64   * 2);
    ushort_t* xb    = (ushort_t*)alloc((size_t)BL * DIM * 2);
    float*    xr    = (float*)   alloc((size_t)BL * 4096 * 4);
    float*    hf    = (float*)   alloc((size_t)BL * DINNER * 4);
    ushort_t* hb    = (ushort_t*)alloc((size_t)BL * DINNER * 2);
    float*    xdbl  = (float*)   alloc((size_t)BL * XDBLW * 4);
    ushort_t* xdblb = (ushort_t*)alloc((size_t)BL * XDBLW * 2);
    float*    delta = (float*)   alloc((size_t)BL * DINNER * 4);
    ushort_t* yb    = (ushort_t*)alloc((size_t)BL * DINNER * 2);
    float*    Pbuf  = (float*)   alloc((size_t)BATCH * NCHUNK * DINNER * NSTATE * 4);
    float*    Sbuf  = (float*)   alloc((size_t)BATCH * NCHUNK * DINNER * NSTATE * 4);
    (void)ws_size;

    dim3 tb(32, 8);
    transpose_f32_bf16<<<dim3(4096/32, 1024/32), tb, 0, stream>>>(Win,  WtIn,  1024, 4096);
    transpose_f32_bf16<<<dim3(1024/32, 2048/32), tb, 0, stream>>>(Wout, WtOut, 2048, 1024);
    transpose_f32_bf16<<<dim3(96/32,   2048/32), tb, 0, stream>>>(Wxp,  WtXp,  2048, 96);
    transpose_f32_bf16<<<dim3(2048/32, 64/32),   tb, 0, stream>>>(Wdt,  WtDt,  64,   2048);
    cvt_f32_bf16<<<dim3((BL*DIM/4 + 255)/256), 256, 0, stream>>>(x, xb, BL*DIM);

    // G1: xr = x @ in_proj_w   (2048 x 4096, K=1024)
    gemm_bt<<<dim3(4096/128, BL/128), 256, 0, stream>>>(
        xb, DIM, WtIn, DIM, BL, 2*DINNER, DIM, xr, nullptr, 2*DINNER, nullptr, 0);

    conv_silu<<<dim3(DINNER/256, BL), 256, 0, stream>>>(xr, convw, convb, hf, hb);

    // G2: xdbl = h @ x_proj_w  (2048 x 96, K=2048)
    gemm_bt<<<dim3(1, BL/128), 256, 0, stream>>>(
        hb, DINNER, WtXp, DINNER, BL, XDBLW, DINNER, xdbl, xdblb, XDBLW, nullptr, 0);

    // G3: delta = softplus(dlt @ dt_proj_w + dt_b)  (2048 x 2048, K=64)
    gemm_bt<<<dim3(DINNER/128, BL/128), 256, 0, stream>>>(
        xdblb, XDBLW, WtDt, DTRANK, BL, DINNER, DTRANK, delta, nullptr, DINNER, dtb, 1);

    // chunked parallel scan
    scan_p1<<<dim3(8 * BATCH * NCHUNK), 256, 0, stream>>>(delta, hf, xdbl, Alog, Pbuf, Sbuf);
    scan_p2<<<dim3(BATCH * DINNER * NSTATE / 256), 256, 0, stream>>>(Pbuf, Sbuf);
    scan_p3<<<dim3(8 * BATCH * NCHUNK), 256, 0, stream>>>(delta, hf, xdbl, xr, Alog, Dp, Sbuf, yb);

    // G4: out = y @ out_proj_w (2048 x 1024, K=2048) -> f32 d_out
    gemm_bt<<<dim3(DIM/128, BL/128), 256, 0, stream>>>(
        yb, DINNER, WtOut, DINNER, BL, DIM, DINNER, out, nullptr, DIM, nullptr, 0);
}

// Round 4
// 253.855 us; speedup vs baseline: 2.5728x; 1.3893x over previous
//
#include <hip/hip_runtime.h>
#include <hip/hip_bf16.h>

// ---- problem dims (compile-time) ----
#define DIM     1024
#define DINNER  2048
#define NSTATE  16
#define DTRANK  64
#define DCONV   4
#define BATCH   2
#define SEQ     1024
#define BL      (BATCH*SEQ)     // 2048 rows
#define XDBLW   96              // DTRANK + 2*NSTATE
#define NCHUNK  64
#define TCHUNK  16              // SEQ / NCHUNK
#define KSLICE  16              // split-K factor for G2

typedef __attribute__((ext_vector_type(4))) float  f32x4;
typedef __attribute__((ext_vector_type(8))) short  bf16x8;
typedef unsigned short ushort_t;

__device__ __forceinline__ ushort_t f2bf(float f) {
    union { float f; unsigned int u; } v; v.f = f;
    unsigned int lsb = (v.u >> 16) & 1u;
    v.u += 0x7fffu + lsb;
    return (ushort_t)(v.u >> 16);
}

typedef __attribute__((address_space(1))) unsigned int gu32_t;
typedef __attribute__((address_space(3))) unsigned int lu32_t;
__device__ __forceinline__ void gload_lds16(const ushort_t* g, ushort_t* l) {
    // async global->LDS, 16B per lane; LDS dest = wave-uniform base + lane*16
    __builtin_amdgcn_global_load_lds((const gu32_t*)(const void*)g,
                                     (lu32_t*)(void*)l, 16, 0, 0);
}

// ---------------- convert f32 -> bf16 (flat) ----------------
__global__ __launch_bounds__(256) void cvt_f32_bf16(
    const float* __restrict__ src, ushort_t* __restrict__ dst, int n)
{
    int i = (blockIdx.x * 256 + threadIdx.x) * 4;
    if (i >= n) return;
    f32x4 v = *(const f32x4*)(src + i);
    ushort_t r0 = f2bf(v[0]), r1 = f2bf(v[1]), r2 = f2bf(v[2]), r3 = f2bf(v[3]);
    *(uint2*)(dst + i) = make_uint2((unsigned)r0 | ((unsigned)r1 << 16),
                                    (unsigned)r2 | ((unsigned)r3 << 16));
}

// ---------------- transpose f32 (R x C) -> bf16 (C x R), 32x32 tiles ----------------
__global__ __launch_bounds__(256) void transpose_f32_bf16(
    const float* __restrict__ src, ushort_t* __restrict__ dst, int R, int C)
{
    __shared__ float tile[32][33];
    const int tx = threadIdx.x;
    const int ty = threadIdx.y;
    const int r0 = blockIdx.y * 32;
    const int c0 = blockIdx.x * 32;
    #pragma unroll
    for (int i = 0; i < 4; ++i) {
        int r = r0 + ty + i * 8;
        tile[ty + i * 8][tx] = src[(size_t)r * C + c0 + tx];
    }
    __syncthreads();
    #pragma unroll
    for (int i = 0; i < 4; ++i) {
        int c = c0 + ty + i * 8;
        dst[(size_t)c * R + r0 + tx] = f2bf(tile[tx][ty + i * 8]);
    }
}

// ======== m97-style MFMA GEMM: C = A(MxK) * Bt(NxK)^T, full 128-tiles ========
// 128x128 tile, 4 waves (2x2 of 64x64), BK=32, linear LDS, global_load_lds x16.
// Requires M,N multiples of 128, K multiple of 32, all rows 16B-aligned.
__global__ __launch_bounds__(256) void gemm_lds(
    const ushort_t* __restrict__ A,  int lda,
    const ushort_t* __restrict__ Bt, int ldb,
    int K,
    float* __restrict__ Cf, int ldc,
    const float* __restrict__ bias, int do_softplus)
{
    __shared__ ushort_t As[128 * 32];   // linear [row][32]
    __shared__ ushort_t Bs[128 * 32];

    const int tid  = threadIdx.x;
    const int m0   = blockIdx.y * 128;
    const int n0   = blockIdx.x * 128;
    const int wid  = tid >> 6;
    const int lane = tid & 63;
    const int wm   = (wid >> 1) * 64;
    const int wn   = (wid & 1) * 64;
    const int lr   = lane & 15;
    const int lk   = (lane >> 4) * 8;

    // staging chunk ids (16B chunks, [row][32] layout: chunk c -> row c>>2, k (c&3)*8)
    const int c0 = wid * 64 + lane;     // issue 0
    const int c1 = 256 + c0;            // issue 1
    const int r0 = c0 >> 2, f0 = (c0 & 3) * 8;
    const int r1 = c1 >> 2, f1 = (c1 & 3) * 8;
    ushort_t* lA0 = &As[(wid * 64) * 8];
    ushort_t* lA1 = &As[(256 + wid * 64) * 8];
    ushort_t* lB0 = &Bs[(wid * 64) * 8];
    ushort_t* lB1 = &Bs[(256 + wid * 64) * 8];

    f32x4 acc[4][4];
    #pragma unroll
    for (int m = 0; m < 4; ++m)
        #pragma unroll
        for (int n = 0; n < 4; ++n)
            acc[m][n] = (f32x4){0.f, 0.f, 0.f, 0.f};

    for (int k0 = 0; k0 < K; k0 += 32) {
        gload_lds16(A  + (size_t)(m0 + r0) * lda + k0 + f0, lA0);
        gload_lds16(A  + (size_t)(m0 + r1) * lda + k0 + f1, lA1);
        gload_lds16(Bt + (size_t)(n0 + r0) * ldb + k0 + f0, lB0);
        gload_lds16(Bt + (size_t)(n0 + r1) * ldb + k0 + f1, lB1);
        __syncthreads();   // drains vmcnt -> LDS tiles ready

        bf16x8 af[4], bfr[4];
        #pragma unroll
        for (int m = 0; m < 4; ++m)
            af[m] = *(const bf16x8*)(&As[(wm + m * 16 + lr) * 32 + lk]);
        #pragma unroll
        for (int n = 0; n < 4; ++n)
            bfr[n] = *(const bf16x8*)(&Bs[(wn + n * 16 + lr) * 32 + lk]);

        #pragma unroll
        for (int m = 0; m < 4; ++m)
            #pragma unroll
            for (int n = 0; n < 4; ++n)
                acc[m][n] = __builtin_amdgcn_mfma_f32_16x16x32_bf16(af[m], bfr[n], acc[m][n], 0, 0, 0);
        __syncthreads();   // protect LDS before next stage
    }

    // epilogue: C/D layout col = lane&15, row = (lane>>4)*4 + r   [m89]
    const int rbase = (lane >> 4) * 4;
    #pragma unroll
    for (int m = 0; m < 4; ++m) {
        #pragma unroll
        for (int n = 0; n < 4; ++n) {
            int col = n0 + wn + n * 16 + lr;
            #pragma unroll
            for (int r = 0; r < 4; ++r) {
                int row = m0 + wm + m * 16 + rbase + r;
                float v = acc[m][n][r];
                if (do_softplus) {
                    v += bias[col];
                    v = (v > 20.f) ? v : log1pf(expf(v));
                }
                Cf[(size_t)row * ldc + col] = v;
            }
        }
    }
}

// ======== G2 split-K: Ppart[ks] = A(128-row tile) * Bt(96xK slice)^T ========
// grid (KSLICE, M/128); wave w handles rows [w*32, w*32+32), all 96 cols.
__global__ __launch_bounds__(256) void gemm_n96_splitk(
    const ushort_t* __restrict__ A,    // BL x 2048 (hb)
    const ushort_t* __restrict__ Bt,   // 96 x 2048 (WtXp)
    float* __restrict__ Ppart)         // [KSLICE][BL][96]
{
    __shared__ ushort_t As[128 * 40];
    __shared__ ushort_t Bs[96 * 40];

    const int tid   = threadIdx.x;
    const int ks    = blockIdx.x;
    const int m0    = blockIdx.y * 128;
    const int kbase = ks * (DINNER / KSLICE);   // 128
    const int wid   = tid >> 6;
    const int lane  = tid & 63;
    const int wm    = wid * 32;
    const int lr    = lane & 15;
    const int lk    = (lane >> 4) * 8;

    f32x4 acc[2][6];
    #pragma unroll
    for (int m = 0; m < 2; ++m)
        #pragma unroll
        for (int n = 0; n < 6; ++n)
            acc[m][n] = (f32x4){0.f, 0.f, 0.f, 0.f};

    for (int k0 = kbase; k0 < kbase + DINNER / KSLICE; k0 += 32) {
        #pragma unroll
        for (int c = 0; c < 2; ++c) {
            int cid = tid + c * 256;
            int row = cid >> 2, ck = (cid & 3) * 8;
            *(uint4*)(&As[row * 40 + ck]) =
                *(const uint4*)(A + (size_t)(m0 + row) * DINNER + k0 + ck);
        }
        {
            int row = tid >> 2, ck = (tid & 3) * 8;
            *(uint4*)(&Bs[row * 40 + ck]) =
                *(const uint4*)(Bt + (size_t)row * DINNER + k0 + ck);
            if (tid < 128) {
                int cid = 256 + tid;
                int row2 = cid >> 2, ck2 = (cid & 3) * 8;
                *(uint4*)(&Bs[row2 * 40 + ck2]) =
                    *(const uint4*)(Bt + (size_t)row2 * DINNER + k0 + ck2);
            }
        }
        __syncthreads();

        bf16x8 af[2], bfr[6];
        #pragma unroll
        for (int m = 0; m < 2; ++m)
            af[m] = *(const bf16x8*)(&As[(wm + m * 16 + lr) * 40 + lk]);
        #pragma unroll
        for (int n = 0; n < 6; ++n)
            bfr[n] = *(const bf16x8*)(&Bs[(n * 16 + lr) * 40 + lk]);

        #pragma unroll
        for (int m = 0; m < 2; ++m)
            #pragma unroll
            for (int n = 0; n < 6; ++n)
                acc[m][n] = __builtin_amdgcn_mfma_f32_16x16x32_bf16(af[m], bfr[n], acc[m][n], 0, 0, 0);
        __syncthreads();
    }

    const int rbase = (lane >> 4) * 4;
    #pragma unroll
    for (int m = 0; m < 2; ++m) {
        #pragma unroll
        for (int n = 0; n < 6; ++n) {
            int col = n * 16 + lr;
            #pragma unroll
            for (int r = 0; r < 4; ++r) {
                int row = m0 + wm + m * 16 + rbase + r;
                Ppart[((size_t)ks * BL + row) * XDBLW + col] = acc[m][n][r];
            }
        }
    }
}

// reduce split-K partials -> xdbl (f32) + xdblb (bf16)
__global__ __launch_bounds__(256) void g2_reduce(
    const float* __restrict__ Ppart, float* __restrict__ xdbl, ushort_t* __restrict__ xdblb)
{
    int idx = blockIdx.x * 256 + threadIdx.x;     // BL * 24 groups of 4 cols
    int row = idx / 24, cg = (idx % 24) * 4;
    f32x4 s = (f32x4){0.f, 0.f, 0.f, 0.f};
    #pragma unroll
    for (int ks = 0; ks < KSLICE; ++ks)
        s += *(const f32x4*)(Ppart + ((size_t)ks * BL + row) * XDBLW + cg);
    *(f32x4*)(xdbl + (size_t)row * XDBLW + cg) = s;
    ushort_t b0 = f2bf(s[0]), b1 = f2bf(s[1]), b2 = f2bf(s[2]), b3 = f2bf(s[3]);
    *(uint2*)(xdblb + (size_t)row * XDBLW + cg) =
        make_uint2((unsigned)b0 | ((unsigned)b1 << 16), (unsigned)b2 | ((unsigned)b3 << 16));
}

// ---------------- depthwise causal conv(4) + bias + SiLU ----------------
__global__ __launch_bounds__(256) void conv_silu(
    const float* __restrict__ xr,
    const float* __restrict__ convw,
    const float* __restrict__ convb,
    float* __restrict__ hf, ushort_t* __restrict__ hb)
{
    const int d  = blockIdx.x * 256 + threadIdx.x;
    const int bt = blockIdx.y;
    const int t  = bt & (SEQ - 1);

    float acc = convb[d];
    #pragma unroll
    for (int j = 0; j < DCONV; ++j) {
        int tt = t + j - (DCONV - 1);
        if (tt >= 0)
            acc += convw[d * DCONV + j] * xr[(size_t)(bt + j - (DCONV - 1)) * 4096 + d];
    }
    float h = acc / (1.f + expf(-acc));
    hf[(size_t)bt * DINNER + d] = h;
    hb[(size_t)bt * DINNER + d] = f2bf(h);
}

// ================= chunked parallel selective scan =================
__global__ __launch_bounds__(256) void scan_p1(
    const float* __restrict__ delta,
    const float* __restrict__ hf,
    const float* __restrict__ xdbl,
    const float* __restrict__ Alog,
    float* __restrict__ Pbuf,
    float* __restrict__ Sbuf)
{
    const int d  = (blockIdx.x & 7) * 256 + threadIdx.x;
    const int bc = blockIdx.x >> 3;
    const int b  = bc >> 6;
    const int c  = bc & (NCHUNK - 1);
    const int t0 = c * TCHUNK;

    float A[NSTATE];
    #pragma unroll
    for (int q = 0; q < 4; ++q) {
        f32x4 al = *(const f32x4*)(Alog + (size_t)d * NSTATE + q * 4);
        #pragma unroll
        for (int j = 0; j < 4; ++j) A[q * 4 + j] = -expf(al[j]);
    }

    float s[NSTATE], pp[NSTATE];
    #pragma unroll
    for (int n = 0; n < NSTATE; ++n) { s[n] = 0.f; pp[n] = 1.f; }

    for (int tt = 0; tt < TCHUNK; ++tt) {
        const size_t row = (size_t)(b * SEQ + t0 + tt);
        float dl = delta[row * DINNER + d];
        float hv = hf[row * DINNER + d];
        float dlh = dl * hv;
        float Bv[NSTATE];
        #pragma unroll
        for (int q = 0; q < 4; ++q) {
            f32x4 bv = *(const f32x4*)(xdbl + row * XDBLW + DTRANK + q * 4);
            #pragma unroll
            for (int j = 0; j < 4; ++j) Bv[q * 4 + j] = bv[j];
        }
        #pragma unroll
        for (int n = 0; n < NSTATE; ++n) {
            float a = expf(dl * A[n]);
            s[n]  = fmaf(a, s[n], dlh * Bv[n]);
            pp[n] *= a;
        }
    }

    const size_t o = (((size_t)b * NCHUNK + c) * DINNER + d) * NSTATE;
    #pragma unroll
    for (int q = 0; q < 4; ++q) {
        *(f32x4*)(Sbuf + o + q * 4) = (f32x4){s[q*4+0], s[q*4+1], s[q*4+2], s[q*4+3]};
        *(f32x4*)(Pbuf + o + q * 4) = (f32x4){pp[q*4+0], pp[q*4+1], pp[q*4+2], pp[q*4+3]};
    }
}

__global__ __launch_bounds__(256) void scan_p2(
    const float* __restrict__ Pbuf, float* __restrict__ Sbuf)
{
    const int tid = blockIdx.x * 256 + threadIdx.x;
    const int n = tid & 15;
    const int d = (tid >> 4) & (DINNER - 1);
    const int b = tid >> 15;
    const size_t stride = (size_t)DINNER * NSTATE;
    size_t idx = ((size_t)b * NCHUNK * DINNER + d) * NSTATE + n;
    float cin = 0.f;
    for (int c = 0; c < NCHUNK; ++c, idx += stride) {
        float S = Sbuf[idx];
        float P = Pbuf[idx];
        Sbuf[idx] = cin;
        cin = fmaf(P, cin, S);
    }
}

__global__ __launch_bounds__(256) void scan_p3(
    const float* __restrict__ delta,
    const float* __restrict__ hf,
    const float* __restrict__ xdbl,
    const float* __restrict__ xr,
    const float* __restrict__ Alog,
    const float* __restrict__ Dp,
    const float* __restrict__ Sbuf,
    ushort_t* __restrict__ yb)
{
    const int d  = (blockIdx.x & 7) * 256 + threadIdx.x;
    const int bc = blockIdx.x >> 3;
    const int b  = bc >> 6;
    const int c  = bc & (NCHUNK - 1);
    const int t0 = c * TCHUNK;

    float A[NSTATE];
    #pragma unroll
    for (int q = 0; q < 4; ++q) {
        f32x4 al = *(const f32x4*)(Alog + (size_t)d * NSTATE + q * 4);
        #pragma unroll
        for (int j = 0; j < 4; ++j) A[q * 4 + j] = -expf(al[j]);
    }
    const float Dd = Dp[d];

    float s[NSTATE];
    const size_t o = (((size_t)b * NCHUNK + c) * DINNER + d) * NSTATE;
    #pragma unroll
    for (int q = 0; q < 4; ++q) {
        f32x4 sv = *(const f32x4*)(Sbuf + o + q * 4);
        #pragma unroll
        for (int j = 0; j < 4; ++j) s[q * 4 + j] = sv[j];
    }

    for (int tt = 0; tt < TCHUNK; ++tt) {
        const size_t row = (size_t)(b * SEQ + t0 + tt);
        float dl = delta[row * DINNER + d];
        float hv = hf[row * DINNER + d];
        float rv = xr[row * 4096 + DINNER + d];
        float dlh = dl * hv;
        float Bv[NSTATE], Cv[NSTATE];
        #pragma unroll
        for (int q = 0; q < 4; ++q) {
            f32x4 bv = *(const f32x4*)(xdbl + row * XDBLW + DTRANK + q * 4);
            f32x4 cv = *(const f32x4*)(xdbl + row * XDBLW + DTRANK + NSTATE + q * 4);
            #pragma unroll
            for (int j = 0; j < 4; ++j) { Bv[q*4+j] = bv[j]; Cv[q*4+j] = cv[j]; }
        }
        float y = 0.f;
        #pragma unroll
        for (int n = 0; n < NSTATE; ++n) {
            float a = expf(dl * A[n]);
            s[n] = fmaf(a, s[n], dlh * Bv[n]);
            y = fmaf(s[n], Cv[n], y);
        }
        y = fmaf(hv, Dd, y);
        float sig = 1.f / (1.f + expf(-rv));
        y *= rv * sig;
        yb[row * DINNER + d] = f2bf(y);
    }
}

extern "C" void kernel_launch(void* const* d_in, const int* in_sizes, int n_in,
                              void* d_out, int out_size, void* d_ws, size_t ws_size,
                              hipStream_t stream)
{
    const float* x     = (const float*)d_in[0];
    const float* Win   = (const float*)d_in[1];
    const float* convw = (const float*)d_in[2];
    const float* convb = (const float*)d_in[3];
    const float* Wxp   = (const float*)d_in[4];
    const float* Wdt   = (const float*)d_in[5];
    const float* dtb   = (const float*)d_in[6];
    const float* Alog  = (const float*)d_in[7];
    const float* Dp    = (const float*)d_in[8];
    const float* Wout  = (const float*)d_in[9];
    float* out = (float*)d_out;

    char* base = (char*)d_ws; size_t off = 0;
    auto alloc = [&](size_t bytes) -> char* {
        char* q = base + off;
        off = (off + bytes + 255) & ~(size_t)255;
        return q;
    };
    ushort_t* WtIn  = (ushort_t*)alloc((size_t)4096 * 1024 * 2);
    ushort_t* WtOut = (ushort_t*)alloc((size_t)1024 * 2048 * 2);
    ushort_t* WtXp  = (ushort_t*)alloc((size_t)96   * 2048 * 2);
    ushort_t* WtDt  = (ushort_t*)alloc((size_t)2048 * 64   * 2);
    ushort_t* xb    = (ushort_t*)alloc((size_t)BL * DIM * 2);
    float*    xr    = (float*)   alloc((size_t)BL * 4096 * 4);
    float*    hf    = (float*)   alloc((size_t)BL * DINNER * 4);
    ushort_t* hb    = (ushort_t*)alloc((size_t)BL * DINNER * 2);
    float*    xdbl  = (float*)   alloc((size_t)BL * XDBLW * 4);
    ushort_t* xdblb = (ushort_t*)alloc((size_t)BL * XDBLW * 2);
    float*    delta = (float*)   alloc((size_t)BL * DINNER * 4);
    ushort_t* yb    = (ushort_t*)alloc((size_t)BL * DINNER * 2);
    float*    Pbuf  = (float*)   alloc((size_t)BATCH * NCHUNK * DINNER * NSTATE * 4);  // 16 MB
    float*    Sbuf  = (float*)   alloc((size_t)BATCH * NCHUNK * DINNER * NSTATE * 4);
    // G2 split-K partials alias Pbuf (12.6 MB <= 16 MB; dead before scan_p1 writes Pbuf)
    float*    Ppart = Pbuf;
    (void)ws_size;

    dim3 tb(32, 8);
    transpose_f32_bf16<<<dim3(4096/32, 1024/32), tb, 0, stream>>>(Win,  WtIn,  1024, 4096);
    transpose_f32_bf16<<<dim3(1024/32, 2048/32), tb, 0, stream>>>(Wout, WtOut, 2048, 1024);
    transpose_f32_bf16<<<dim3(96/32,   2048/32), tb, 0, stream>>>(Wxp,  WtXp,  2048, 96);
    transpose_f32_bf16<<<dim3(2048/32, 64/32),   tb, 0, stream>>>(Wdt,  WtDt,  64,   2048);
    cvt_f32_bf16<<<dim3((BL*DIM/4 + 255)/256), 256, 0, stream>>>(x, xb, BL*DIM);

    // G1: xr = x @ in_proj_w   (2048 x 4096, K=1024)
    gemm_lds<<<dim3(4096/128, BL/128), 256, 0, stream>>>(
        xb, DIM, WtIn, DIM, DIM, xr, 2*DINNER, nullptr, 0);

    conv_silu<<<dim3(DINNER/256, BL), 256, 0, stream>>>(xr, convw, convb, hf, hb);

    // G2: xdbl = h @ x_proj_w  (2048 x 96, K=2048) via split-K + reduce
    gemm_n96_splitk<<<dim3(KSLICE, BL/128), 256, 0, stream>>>(hb, WtXp, Ppart);
    g2_reduce<<<dim3(BL * 24 / 256), 256, 0, stream>>>(Ppart, xdbl, xdblb);

    // G3: delta = softplus(dlt @ dt_proj_w + dt_b)  (2048 x 2048, K=64)
    gemm_lds<<<dim3(DINNER/128, BL/128), 256, 0, stream>>>(
        xdblb, XDBLW, WtDt, DTRANK, DTRANK, delta, DINNER, dtb, 1);

    // chunked parallel scan
    scan_p1<<<dim3(8 * BATCH * NCHUNK), 256, 0, stream>>>(delta, hf, xdbl, Alog, Pbuf, Sbuf);
    scan_p2<<<dim3(BATCH * DINNER * NSTATE / 256), 256, 0, stream>>>(Pbuf, Sbuf);
    scan_p3<<<dim3(8 * BATCH * NCHUNK), 256, 0, stream>>>(delta, hf, xdbl, xr, Alog, Dp, Sbuf, yb);

    // G4: out = y @ out_proj_w (2048 x 1024, K=2048) -> f32 d_out
    gemm_lds<<<dim3(DIM/128, BL/128), 256, 0, stream>>>(
        yb, DINNER, WtOut, DINNER, DINNER, out, DIM, nullptr, 0);
}